// Round 1
// baseline (418.967 us; speedup 1.0000x reference)
//
#include <hip/hip_runtime.h>
#include <stdint.h>

#define DIM 128
#define NPROJ 256
#define TPB 128                    // tokens per block (4 waves x 32)
#define TAU 0.016f                 // refine threshold on |k_proj_f16| (~7 sigma of f16 dot err)
#define QCAP 512
#define DEQ 0.004895758348888673f  // sqrt(pi/2)/256

typedef _Float16 f16x8 __attribute__((ext_vector_type(8)));
typedef float f32x4 __attribute__((ext_vector_type(4)));

// ---- prep: S fp32 -> f16 B-fragments, pre-swizzled into MFMA lane order ----
// frag fid = c*8 + ks*2 + f; lane l holds B[n=p][k=d]: p = c*32 + f*16 + (l&15),
// d = ks*32 + (l>>4)*8 + j
__global__ __launch_bounds__(256) void qjl_prep(const float* __restrict__ Sg,
                                                _Float16* __restrict__ ws) {
    int t = blockIdx.x * 256 + threadIdx.x;   // 0..4095
    int lane = t & 63, fid = t >> 6;          // 64 frags
    int f = fid & 1, ks = (fid >> 1) & 3, c = fid >> 3;
    int p = c * 32 + f * 16 + (lane & 15);
    int d0 = ks * 32 + (lane >> 4) * 8;
    const float4* s4 = (const float4*)(Sg + p * DIM + d0);
    float4 a = s4[0], b = s4[1];
    f16x8 h = {(_Float16)a.x, (_Float16)a.y, (_Float16)a.z, (_Float16)a.w,
               (_Float16)b.x, (_Float16)b.y, (_Float16)b.z, (_Float16)b.w};
    *(f16x8*)(ws + (size_t)fid * 512 + lane * 8) = h;
}

// load the 4 B-frags of (chunk C, 16-proj tile T) into named buffer
#define LOADT(buf, C, T)                                                             \
    { _Pragma("unroll")                                                              \
      for (int ks = 0; ks < 4; ++ks)                                                 \
          buf[ks] = *(const f16x8*)(ws + (size_t)((C) * 8 + ks * 2 + (T)) * 512 + lane * 8); }

// A fragments (K or Q rows) fp32 -> f16 into dst[2][4]
#define LOADA(dst, src)                                                              \
    { _Pragma("unroll")                                                              \
      for (int rb = 0; rb < 2; ++rb) {                                               \
          const float* rp = (src) + (tok0 + wv * 32 + rb * 16 + m) * DIM;            \
          _Pragma("unroll")                                                          \
          for (int ks = 0; ks < 4; ++ks) {                                           \
              int d0 = ks * 32 + quad * 8;                                           \
              float4 x = *(const float4*)(rp + d0);                                  \
              float4 y = *(const float4*)(rp + d0 + 4);                              \
              dst[rb][ks] = (f16x8){(_Float16)x.x, (_Float16)x.y, (_Float16)x.z, (_Float16)x.w, \
                                    (_Float16)y.x, (_Float16)y.y, (_Float16)y.z, (_Float16)y.w}; } } }

// Fused step: k_proj and q_proj on the same B tile; est += sign(k)*q directly.
// Near-zero k_proj -> candidate queue (stores the f16 sign actually applied).
#define F_STEP(C, T, buf)                                                            \
    { f32x4 k0 = {0,0,0,0}, k1 = {0,0,0,0}, q0 = {0,0,0,0}, q1 = {0,0,0,0};          \
      _Pragma("unroll")                                                              \
      for (int ks = 0; ks < 4; ++ks) {                                               \
          k0 = __builtin_amdgcn_mfma_f32_16x16x32_f16(ak[0][ks], buf[ks], k0, 0,0,0);\
          k1 = __builtin_amdgcn_mfma_f32_16x16x32_f16(ak[1][ks], buf[ks], k1, 0,0,0);\
          q0 = __builtin_amdgcn_mfma_f32_16x16x32_f16(aq[0][ks], buf[ks], q0, 0,0,0);\
          q1 = __builtin_amdgcn_mfma_f32_16x16x32_f16(aq[1][ks], buf[ks], q1, 0,0,0);\
      }                                                                              \
      _Pragma("unroll")                                                              \
      for (int r = 0; r < 4; ++r) {                                                  \
          uint32_t s0 = __float_as_uint(k0[r]) & 0x80000000u;                        \
          uint32_t s1 = __float_as_uint(k1[r]) & 0x80000000u;                        \
          est[r]     += __uint_as_float(__float_as_uint(q0[r]) ^ s0);                \
          est[4 + r] += __uint_as_float(__float_as_uint(q1[r]) ^ s1);                \
          if (__builtin_expect(fabsf(k0[r]) < TAU, 0)) {                             \
              int idx = atomicAdd(&qn, 1);                                           \
              if (idx < QCAP) qmeta[idx] = (uint32_t)(wv * 32 + quad * 4 + r)        \
                  | ((uint32_t)((C) * 32 + (T) * 16 + m) << 8)                       \
                  | ((s0 ? 0u : 1u) << 16);                                          \
          }                                                                          \
          if (__builtin_expect(fabsf(k1[r]) < TAU, 0)) {                             \
              int idx = atomicAdd(&qn, 1);                                           \
              if (idx < QCAP) qmeta[idx] = (uint32_t)(wv * 32 + 16 + quad * 4 + r)   \
                  | ((uint32_t)((C) * 32 + (T) * 16 + m) << 8)                       \
                  | ((s1 ? 0u : 1u) << 16);                                          \
          } } }

__global__ __launch_bounds__(256, 3) void qjl_main(
    const float* __restrict__ qg, const float* __restrict__ kg,
    const float* __restrict__ Sg, const _Float16* __restrict__ ws,
    float* __restrict__ out)
{
    __shared__ float    est_s[TPB];
    __shared__ uint32_t qmeta[QCAP];
    __shared__ int      qn;

    const int tid = threadIdx.x, lane = tid & 63, wv = tid >> 6;
    const int m = lane & 15, quad = lane >> 4;
    const long tok0 = (long)blockIdx.x * TPB;
    if (tid == 0) qn = 0;
    __syncthreads();

    f16x8 ak[2][4], aq[2][4];  // A fragments: K rows and Q rows, both resident
    f16x8 tA[4], tB[4];        // B half-chunk double buffer
    float est[8] = {0.f, 0.f, 0.f, 0.f, 0.f, 0.f, 0.f, 0.f};

    // ================= single fused pass =================
    LOADT(tA, 0, 0);
    LOADA(ak, kg);
    LOADA(aq, qg);
    LOADT(tB, 0, 1);
    F_STEP(0, 0, tA); LOADT(tA, 1, 0);
    F_STEP(0, 1, tB); LOADT(tB, 1, 1);
    F_STEP(1, 0, tA); LOADT(tA, 2, 0);
    F_STEP(1, 1, tB); LOADT(tB, 2, 1);
    F_STEP(2, 0, tA); LOADT(tA, 3, 0);
    F_STEP(2, 1, tB); LOADT(tB, 3, 1);
    F_STEP(3, 0, tA); LOADT(tA, 4, 0);
    F_STEP(3, 1, tB); LOADT(tB, 4, 1);
    F_STEP(4, 0, tA); LOADT(tA, 5, 0);
    F_STEP(4, 1, tB); LOADT(tB, 5, 1);
    F_STEP(5, 0, tA); LOADT(tA, 6, 0);
    F_STEP(5, 1, tB); LOADT(tB, 6, 1);
    F_STEP(6, 0, tA); LOADT(tA, 7, 0);
    F_STEP(6, 1, tB); LOADT(tB, 7, 1);
    F_STEP(7, 0, tA);
    F_STEP(7, 1, tB);

    // ---- reduce est over the 16 proj-lanes ----
    #pragma unroll
    for (int rb = 0; rb < 2; ++rb) {
        #pragma unroll
        for (int r = 0; r < 4; ++r) {
            float e = est[rb * 4 + r];
            e += __shfl_xor(e, 1);
            e += __shfl_xor(e, 2);
            e += __shfl_xor(e, 4);
            e += __shfl_xor(e, 8);
            if (m == 0) est_s[wv * 32 + rb * 16 + quad * 4 + r] = DEQ * e;
        }
    }
    __syncthreads();

    // ---- refine: per-thread exact fp64 dots; patch est on sign flips ----
    int nc = qn < QCAP ? qn : QCAP;
    for (int i = tid; i < nc; i += 256) {
        uint32_t mm = qmeta[i];
        int tl = mm & 255;
        int p  = (mm >> 8) & 255;
        int sf = (mm >> 16) & 1;
        const float4* kr = (const float4*)(kg + (tok0 + tl) * DIM);
        const float4* qr = (const float4*)(qg + (tok0 + tl) * DIM);
        const float4* sr = (const float4*)(Sg + (long)p * DIM);
        double dk = 0.0, dq = 0.0;
        #pragma unroll 8
        for (int j = 0; j < 32; ++j) {
            float4 kv4 = kr[j], qv4 = qr[j], sv4 = sr[j];
            dk += (double)kv4.x * (double)sv4.x + (double)kv4.y * (double)sv4.y
                + (double)kv4.z * (double)sv4.z + (double)kv4.w * (double)sv4.w;
            dq += (double)qv4.x * (double)sv4.x + (double)qv4.y * (double)sv4.y
                + (double)qv4.z * (double)sv4.z + (double)qv4.w * (double)sv4.w;
        }
        int st = (dk > 0.0) ? 1 : 0;
        if (st != sf) {
            float sg = sf ? 1.f : -1.f;
            atomicAdd(&est_s[tl], -2.f * DEQ * (float)dq * sg);
        }
    }
    __syncthreads();

    if (tid < TPB) out[tok0 + tid] = est_s[tid];
}

extern "C" void kernel_launch(void* const* d_in, const int* in_sizes, int n_in,
                              void* d_out, int out_size, void* d_ws, size_t ws_size,
                              hipStream_t stream) {
    const float* q = (const float*)d_in[0];
    const float* k = (const float*)d_in[1];
    const float* S = (const float*)d_in[2];
    float* out = (float*)d_out;
    _Float16* ws = (_Float16*)d_ws;
    hipLaunchKernelGGL(qjl_prep, dim3(16), dim3(256), 0, stream, S, ws);
    int nblocks = out_size / TPB;   // 262144 / 128 = 2048
    hipLaunchKernelGGL(qjl_main, dim3(nblocks), dim3(256), 0, stream, q, k, S, ws, out);
}

// Round 3
// 387.071 us; speedup vs baseline: 1.0824x; 1.0824x over previous
//
#include <hip/hip_runtime.h>
#include <stdint.h>

#define DIM 128
#define NPROJ 256
#define TPB 128                    // tokens per block (4 waves x 32)
#define TAU 0.016f                 // refine threshold on |k_proj_f16| (~7 sigma of f16 dot err)
#define QCAP 512
#define DEQ 0.004895758348888673f  // sqrt(pi/2)/256

typedef _Float16 f16x8 __attribute__((ext_vector_type(8)));
typedef float f32x4 __attribute__((ext_vector_type(4)));

// ---- prep: S fp32 -> f16 B-fragments, pre-swizzled into MFMA lane order ----
// frag fid = c*8 + ks*2 + f; lane l holds B[n=p][k=d]: p = c*32 + f*16 + (l&15),
// d = ks*32 + (l>>4)*8 + j
__global__ __launch_bounds__(256) void qjl_prep(const float* __restrict__ Sg,
                                                _Float16* __restrict__ ws) {
    int t = blockIdx.x * 256 + threadIdx.x;   // 0..4095
    int lane = t & 63, fid = t >> 6;          // 64 frags
    int f = fid & 1, ks = (fid >> 1) & 3, c = fid >> 3;
    int p = c * 32 + f * 16 + (lane & 15);
    int d0 = ks * 32 + (lane >> 4) * 8;
    const float4* s4 = (const float4*)(Sg + p * DIM + d0);
    float4 a = s4[0], b = s4[1];
    f16x8 h = {(_Float16)a.x, (_Float16)a.y, (_Float16)a.z, (_Float16)a.w,
               (_Float16)b.x, (_Float16)b.y, (_Float16)b.z, (_Float16)b.w};
    *(f16x8*)(ws + (size_t)fid * 512 + lane * 8) = h;
}

// load the 4 B-frags of (chunk C, 16-proj tile T) into named buffer
#define LOADT(buf, C, T)                                                             \
    { _Pragma("unroll")                                                              \
      for (int ks = 0; ks < 4; ++ks)                                                 \
          buf[ks] = *(const f16x8*)(ws + (size_t)((C) * 8 + ks * 2 + (T)) * 512 + lane * 8); }

// A fragments (K or Q rows) fp32 -> f16 into dst[2][4]
#define LOADA(dst, src)                                                              \
    { _Pragma("unroll")                                                              \
      for (int rb = 0; rb < 2; ++rb) {                                               \
          const float* rp = (src) + (tok0 + wv * 32 + rb * 16 + m) * DIM;            \
          _Pragma("unroll")                                                          \
          for (int ks = 0; ks < 4; ++ks) {                                           \
              int d0 = ks * 32 + quad * 8;                                           \
              float4 x = *(const float4*)(rp + d0);                                  \
              float4 y = *(const float4*)(rp + d0 + 4);                              \
              dst[rb][ks] = (f16x8){(_Float16)x.x, (_Float16)x.y, (_Float16)x.z, (_Float16)x.w, \
                                    (_Float16)y.x, (_Float16)y.y, (_Float16)y.z, (_Float16)y.w}; } } }

// Fused step: k_proj and q_proj on the same B tile; est += sign(k)*q directly.
// Near-zero k_proj -> candidate queue (stores the f16 sign actually applied).
#define F_STEP(C, T, buf)                                                            \
    { f32x4 k0 = {0,0,0,0}, k1 = {0,0,0,0}, q0 = {0,0,0,0}, q1 = {0,0,0,0};          \
      _Pragma("unroll")                                                              \
      for (int ks = 0; ks < 4; ++ks) {                                               \
          k0 = __builtin_amdgcn_mfma_f32_16x16x32_f16(ak[0][ks], buf[ks], k0, 0,0,0);\
          k1 = __builtin_amdgcn_mfma_f32_16x16x32_f16(ak[1][ks], buf[ks], k1, 0,0,0);\
          q0 = __builtin_amdgcn_mfma_f32_16x16x32_f16(aq[0][ks], buf[ks], q0, 0,0,0);\
          q1 = __builtin_amdgcn_mfma_f32_16x16x32_f16(aq[1][ks], buf[ks], q1, 0,0,0);\
      }                                                                              \
      _Pragma("unroll")                                                              \
      for (int r = 0; r < 4; ++r) {                                                  \
          uint32_t s0 = __float_as_uint(k0[r]) & 0x80000000u;                        \
          uint32_t s1 = __float_as_uint(k1[r]) & 0x80000000u;                        \
          est[r]     += __uint_as_float(__float_as_uint(q0[r]) ^ s0);                \
          est[4 + r] += __uint_as_float(__float_as_uint(q1[r]) ^ s1);                \
          if (__builtin_expect(fabsf(k0[r]) < TAU, 0)) {                             \
              int idx = atomicAdd(&qn, 1);                                           \
              if (idx < QCAP) qmeta[idx] = (uint32_t)(wv * 32 + quad * 4 + r)        \
                  | ((uint32_t)((C) * 32 + (T) * 16 + m) << 8)                       \
                  | ((s0 ? 0u : 1u) << 16);                                          \
          }                                                                          \
          if (__builtin_expect(fabsf(k1[r]) < TAU, 0)) {                             \
              int idx = atomicAdd(&qn, 1);                                           \
              if (idx < QCAP) qmeta[idx] = (uint32_t)(wv * 32 + 16 + quad * 4 + r)   \
                  | ((uint32_t)((C) * 32 + (T) * 16 + m) << 8)                       \
                  | ((s1 ? 0u : 1u) << 16);                                          \
          } } }

// waves_per_eu(2,3): cap the backend's occupancy TARGET at 3 waves/EU so the
// ~135-VGPR live set gets a 168-reg budget. Round 1 evidence: with only a
// floor (launch_bounds(256,3)) the allocator targeted 6 waves/EU, allocated
// 84 VGPRs, and spilled ~530 MB of scratch traffic (WRITE_SIZE 5->347 MB,
// MfmaUtil 8.7->5.5, dur 152->243 us).
__global__
__attribute__((amdgpu_flat_work_group_size(256, 256), amdgpu_waves_per_eu(2, 3)))
void qjl_main(
    const float* __restrict__ qg, const float* __restrict__ kg,
    const float* __restrict__ Sg, const _Float16* __restrict__ ws,
    float* __restrict__ out)
{
    __shared__ float    est_s[TPB];
    __shared__ uint32_t qmeta[QCAP];
    __shared__ int      qn;

    const int tid = threadIdx.x, lane = tid & 63, wv = tid >> 6;
    const int m = lane & 15, quad = lane >> 4;
    const long tok0 = (long)blockIdx.x * TPB;
    if (tid == 0) qn = 0;
    __syncthreads();

    f16x8 ak[2][4], aq[2][4];  // A fragments: K rows and Q rows, both resident
    f16x8 tA[4], tB[4];        // B half-chunk double buffer
    float est[8] = {0.f, 0.f, 0.f, 0.f, 0.f, 0.f, 0.f, 0.f};

    // ================= single fused pass =================
    // HBM loads (high latency) issued first, then the L2-resident B tiles.
    LOADA(ak, kg);
    LOADA(aq, qg);
    LOADT(tA, 0, 0);
    LOADT(tB, 0, 1);
    F_STEP(0, 0, tA); LOADT(tA, 1, 0);
    F_STEP(0, 1, tB); LOADT(tB, 1, 1);
    F_STEP(1, 0, tA); LOADT(tA, 2, 0);
    F_STEP(1, 1, tB); LOADT(tB, 2, 1);
    F_STEP(2, 0, tA); LOADT(tA, 3, 0);
    F_STEP(2, 1, tB); LOADT(tB, 3, 1);
    F_STEP(3, 0, tA); LOADT(tA, 4, 0);
    F_STEP(3, 1, tB); LOADT(tB, 4, 1);
    F_STEP(4, 0, tA); LOADT(tA, 5, 0);
    F_STEP(4, 1, tB); LOADT(tB, 5, 1);
    F_STEP(5, 0, tA); LOADT(tA, 6, 0);
    F_STEP(5, 1, tB); LOADT(tB, 6, 1);
    F_STEP(6, 0, tA); LOADT(tA, 7, 0);
    F_STEP(6, 1, tB); LOADT(tB, 7, 1);
    F_STEP(7, 0, tA);
    F_STEP(7, 1, tB);

    // ---- reduce est over the 16 proj-lanes ----
    #pragma unroll
    for (int rb = 0; rb < 2; ++rb) {
        #pragma unroll
        for (int r = 0; r < 4; ++r) {
            float e = est[rb * 4 + r];
            e += __shfl_xor(e, 1);
            e += __shfl_xor(e, 2);
            e += __shfl_xor(e, 4);
            e += __shfl_xor(e, 8);
            if (m == 0) est_s[wv * 32 + rb * 16 + quad * 4 + r] = DEQ * e;
        }
    }
    __syncthreads();

    // ---- refine: per-thread exact fp64 dots; patch est on sign flips ----
    int nc = qn < QCAP ? qn : QCAP;
    for (int i = tid; i < nc; i += 256) {
        uint32_t mm = qmeta[i];
        int tl = mm & 255;
        int p  = (mm >> 8) & 255;
        int sf = (mm >> 16) & 1;
        const float4* kr = (const float4*)(kg + (tok0 + tl) * DIM);
        const float4* qr = (const float4*)(qg + (tok0 + tl) * DIM);
        const float4* sr = (const float4*)(Sg + (long)p * DIM);
        double dk = 0.0, dq = 0.0;
        #pragma unroll 8
        for (int j = 0; j < 32; ++j) {
            float4 kv4 = kr[j], qv4 = qr[j], sv4 = sr[j];
            dk += (double)kv4.x * (double)sv4.x + (double)kv4.y * (double)sv4.y
                + (double)kv4.z * (double)sv4.z + (double)kv4.w * (double)sv4.w;
            dq += (double)qv4.x * (double)sv4.x + (double)qv4.y * (double)sv4.y
                + (double)qv4.z * (double)sv4.z + (double)qv4.w * (double)sv4.w;
        }
        int st = (dk > 0.0) ? 1 : 0;
        if (st != sf) {
            float sg = sf ? 1.f : -1.f;
            atomicAdd(&est_s[tl], -2.f * DEQ * (float)dq * sg);
        }
    }
    __syncthreads();

    if (tid < TPB) out[tok0 + tid] = est_s[tid];
}

extern "C" void kernel_launch(void* const* d_in, const int* in_sizes, int n_in,
                              void* d_out, int out_size, void* d_ws, size_t ws_size,
                              hipStream_t stream) {
    const float* q = (const float*)d_in[0];
    const float* k = (const float*)d_in[1];
    const float* S = (const float*)d_in[2];
    float* out = (float*)d_out;
    _Float16* ws = (_Float16*)d_ws;
    hipLaunchKernelGGL(qjl_prep, dim3(16), dim3(256), 0, stream, S, ws);
    int nblocks = out_size / TPB;   // 262144 / 128 = 2048
    hipLaunchKernelGGL(qjl_main, dim3(nblocks), dim3(256), 0, stream, q, k, S, ws, out);
}